// Round 11
// baseline (204.673 us; speedup 1.0000x reference)
//
#include <hip/hip_runtime.h>
#include <hip/hip_bf16.h>
#include <math.h>

// ---------------------------------------------------------------------------
// IterNorm (64,256,56,56) fp32, g=4 groups of 64 channels.
//  k_gram  : per-block partial Gram (64x64) + channel sums -> slabs
//            [measured R9 probe: ~35us == at its 205MB HBM floor]
//  k_reduce: sum 196 slabs/group -> G, channel sums -> SUM
//  k_solve : 8-wave stacked Newton-Schulz ([P;M]*W one pass), hi/lo bf16 split
//  k_apply : out = wm_bf16 * x_bf16 + beta via MFMA; NT f32x2 stores.
//            [THIS ROUND: launched TWICE -- idempotent attribution probe;
//             apply_cost = dur_us - 134.2]
// ---------------------------------------------------------------------------

#define EPS_F 1e-5f

using f32x4v = __attribute__((ext_vector_type(4))) float;
using f32x2v = __attribute__((ext_vector_type(2))) float;
using short8 = __attribute__((ext_vector_type(8))) short;
using u32x4  = __attribute__((ext_vector_type(4))) unsigned int;
using u32x2  = __attribute__((ext_vector_type(2))) unsigned int;

constexpr int Cc  = 256;
constexpr int HWc = 3136;                 // 56*56
constexpr int CHW = Cc * HWc;             // 802816
constexpr float Mf = 200704.0f;           // 64*3136
constexpr int GX  = 196;                  // 3136 tiles / 196 = 16 tiles/block
constexpr int LDB = 72;                   // bf16 LDS row stride (144 B)

// workspace layout (float offsets)
constexpr int WS_SUM  = 0;                       // 256
constexpr int WS_G    = 256;                     // 4*4096
constexpr int WS_WM   = WS_G + 16384;            // 4*4096
constexpr int WS_BETA = WS_WM + 16384;           // 256
constexpr int WS_SLAB = WS_BETA + 256;           // 784 * 4096 partial Grams
constexpr int WS_SSUM = WS_SLAB + 784 * 4096;    // 784 * 64 partial channel sums

__device__ __forceinline__ unsigned cvtpk(float lo, float hi) {
    __hip_bfloat162 h = __float22bfloat162_rn(float2{lo, hi});
    unsigned u;
    __builtin_memcpy(&u, &h, 4);
    return u;
}

__device__ __forceinline__ unsigned short bf16rn(float v) {
    unsigned u = __builtin_bit_cast(unsigned, v);
    u += 0x7FFFu + ((u >> 16) & 1u);
    return (unsigned short)(u >> 16);
}
__device__ __forceinline__ float frombf(unsigned short h) {
    unsigned u = (unsigned)h << 16;
    return __builtin_bit_cast(float, u);
}

__device__ __forceinline__ f32x4v mfma16(short8 a, short8 b, f32x4v c) {
    return __builtin_amdgcn_mfma_f32_16x16x32_bf16(a, b, c, 0, 0, 0);
}

// ---------------------------------------------------------------------------
// Kernel 1: partial Gram. grid (196,4) x 256 (4 waves). LDS 36.9KB -> 4 blk/CU.
// ---------------------------------------------------------------------------
extern "C" __global__ __launch_bounds__(256, 4)
void k_gram(const float* __restrict__ X, float* __restrict__ ws) {
    __shared__ __align__(16) unsigned short tg[2][2][64 * LDB];
    const int g = blockIdx.y, bx = blockIdx.x, tid = threadIdx.x;
    const int lane = tid & 63, w = tid >> 6;
    const int row = tid >> 2, mo = (tid & 3) << 4;     // load mapping
    const int l15 = lane & 15, lg = lane >> 4;
    const int CBi0 = (w >> 1) << 1, CBj0 = (w & 1) << 1;
    const float* Xg = X + (size_t)g * 64 * HWc;

    f32x4v acc[2][2];
    #pragma unroll
    for (int i = 0; i < 2; ++i)
        #pragma unroll
        for (int j = 0; j < 2; ++j) acc[i][j] = (f32x4v){0.f, 0.f, 0.f, 0.f};
    float csum = 0.0f;

    f32x4v curA[4], curB[4];
    auto loadt = [&](int t, f32x4v* cur) {
        const int b = t / 49, hw0 = (t - b * 49) << 6;
        const float* p = Xg + (size_t)b * CHW + (size_t)row * HWc + hw0 + mo;
        cur[0] = *(const f32x4v*)(p);      cur[1] = *(const f32x4v*)(p + 4);
        cur[2] = *(const f32x4v*)(p + 8);  cur[3] = *(const f32x4v*)(p + 12);
    };
    auto packt = [&](const f32x4v* cur, unsigned short* dstbuf) {
        unsigned pk[8];
        #pragma unroll
        for (int i = 0; i < 4; ++i) {
            csum += (cur[i].x + cur[i].y) + (cur[i].z + cur[i].w);
            pk[2*i]   = cvtpk(cur[i].x, cur[i].y);
            pk[2*i+1] = cvtpk(cur[i].z, cur[i].w);
        }
        unsigned short* dst = dstbuf + row * LDB + mo;
        *(u32x4*)(dst)     = (u32x4){pk[0], pk[1], pk[2], pk[3]};
        *(u32x4*)(dst + 8) = (u32x4){pk[4], pk[5], pk[6], pk[7]};
    };
    auto comp = [&](const unsigned short* T) {
        #pragma unroll
        for (int s = 0; s < 2; ++s) {
            const int ko = 8 * lg + 32 * s;
            const short8 a0 = *(const short8*)&T[(CBi0 * 16      + l15) * LDB + ko];
            const short8 a1 = *(const short8*)&T[((CBi0+1) * 16  + l15) * LDB + ko];
            const short8 b0 = *(const short8*)&T[(CBj0 * 16      + l15) * LDB + ko];
            const short8 b1 = *(const short8*)&T[((CBj0+1) * 16  + l15) * LDB + ko];
            acc[0][0] = mfma16(a0, b0, acc[0][0]);
            acc[0][1] = mfma16(a0, b1, acc[0][1]);
            acc[1][0] = mfma16(a1, b0, acc[1][0]);
            acc[1][1] = mfma16(a1, b1, acc[1][1]);
        }
    };

    loadt(bx, curA);
    loadt(bx + GX, curB);

    int buf = 0;
    for (int kk = 0; kk < 8; ++kk) {
        packt(curA, tg[buf][0]);
        packt(curB, tg[buf][1]);
        __syncthreads();
        if (kk < 7) {                              // prefetch next 2 tiles
            loadt(bx + GX * (2*kk + 2), curA);
            loadt(bx + GX * (2*kk + 3), curB);
        }
        comp(tg[buf][0]);
        comp(tg[buf][1]);
        buf ^= 1;
    }

    csum += __shfl_down(csum, 1, 4);
    csum += __shfl_down(csum, 2, 4);
    if ((tid & 3) == 0)
        ws[WS_SSUM + (g * GX + bx) * 64 + row] = csum;

    float* Gp = ws + WS_SLAB + (size_t)(g * GX + bx) * 4096;
    #pragma unroll
    for (int ci = 0; ci < 2; ++ci)
        #pragma unroll
        for (int cj = 0; cj < 2; ++cj)
            #pragma unroll
            for (int reg = 0; reg < 4; ++reg) {
                const int r = (CBi0 + ci) * 16 + lg * 4 + reg;
                const int c = (CBj0 + cj) * 16 + l15;
                Gp[r * 64 + c] = acc[ci][cj][reg];
            }
}

// ---------------------------------------------------------------------------
// Kernel 1b: reduce slabs. grid (64,4) x 256.
// ---------------------------------------------------------------------------
extern "C" __global__ __launch_bounds__(256)
void k_reduce(float* __restrict__ ws) {
    __shared__ float part[4][64];
    const int g = blockIdx.y, chunk = blockIdx.x, tid = threadIdx.x;
    const int c63 = tid & 63, q = tid >> 6;
    const float* p = ws + WS_SLAB + (size_t)g * GX * 4096
                   + (size_t)(q * 49) * 4096 + chunk * 64 + c63;
    float s = 0.f;
    #pragma unroll 7
    for (int i = 0; i < 49; ++i) { s += *p; p += 4096; }
    part[q][c63] = s;
    __syncthreads();
    if (tid < 64)
        ws[WS_G + g * 4096 + chunk * 64 + tid] =
            (part[0][tid] + part[1][tid]) + (part[2][tid] + part[3][tid]);

    if (chunk == 0 && tid < 64) {
        const float* qq = ws + WS_SSUM + (size_t)g * GX * 64 + tid;
        float a0 = 0.f, a1 = 0.f, a2 = 0.f, a3 = 0.f;
        #pragma unroll 7
        for (int s4 = 0; s4 < 49; ++s4) {
            a0 += qq[0];
            a1 += qq[64];
            a2 += qq[128];
            a3 += qq[192];
            qq += 256;
        }
        ws[WS_SUM + g * 64 + tid] = (a0 + a1) + (a2 + a3);
    }
}

// ---------------------------------------------------------------------------
// Kernel 2: Newton-Schulz via stacked MFMA. 4 blocks x 512 (8 waves).
// ---------------------------------------------------------------------------
extern "C" __global__ __launch_bounds__(512)
void k_solve(const float* __restrict__ weight, const float* __restrict__ bias,
             float* __restrict__ ws) {
    __shared__ __align__(16) unsigned short PMh[128 * LDB], PMl[128 * LDB];
    __shared__ __align__(16) unsigned short Wh[64 * LDB], Wl[64 * LDB];
    __shared__ float mean_s[64], diag_s[64];
    __shared__ float red;

    const int g = blockIdx.x, tid = threadIdx.x;
    const int lane = tid & 63, w = tid >> 6;
    const int l15 = lane & 15, lg = lane >> 4;
    const int r = tid >> 3, ch = (tid & 7) << 3;   // elementwise: row r, 8 cols

    if (tid < 64) mean_s[tid] = ws[WS_SUM + g * 64 + tid] * (1.0f / Mf);
    __syncthreads();

    const float* Gp = ws + WS_G + g * 4096;
    const float mr = mean_s[r];
    float sv[8];
    #pragma unroll
    for (int j = 0; j < 8; ++j) {
        const int c = ch + j;
        float v = Gp[r * 64 + c] * (1.0f / Mf) - mr * mean_s[c];
        if (c == r) { v += EPS_F; diag_s[r] = v; }
        sv[j] = v;
    }
    __syncthreads();
    if (tid == 0) {
        float tr = 0.f;
        #pragma unroll
        for (int i = 0; i < 64; ++i) tr += diag_s[i];
        red = 1.0f / tr;
    }
    __syncthreads();
    const float rtr = red;

    #pragma unroll
    for (int j = 0; j < 8; ++j) {
        const int c = ch + j;
        PMh[r * LDB + c] = (c == r) ? (unsigned short)0x3F80 : (unsigned short)0;
        PMl[r * LDB + c] = 0;
        const float v = sv[j] * rtr;
        const unsigned short h = bf16rn(v);
        PMh[(64 + r) * LDB + c] = h;
        PMl[(64 + r) * LDB + c] = bf16rn(v - frombf(h));
    }
    __syncthreads();

    for (int t = 0; t < 5; ++t) {
        #pragma unroll
        for (int j = 0; j < 8; ++j) {
            const int c = ch + j;
            const float m = frombf(PMh[(64 + r) * LDB + c])
                          + frombf(PMl[(64 + r) * LDB + c]);
            const float wv = ((c == r) ? 1.5f : 0.0f) - 0.5f * m;
            const unsigned short h = bf16rn(wv);
            Wh[r * LDB + c] = h;
            Wl[r * LDB + c] = bf16rn(wv - frombf(h));
        }
        __syncthreads();

        {   // phase1: stacked [P;M] * W, wave w -> stacked row-block w
            short8 ah[2], al[2];
            #pragma unroll
            for (int s = 0; s < 2; ++s) {
                const int off = (16 * w + l15) * LDB + 8 * lg + 32 * s;
                ah[s] = *(const short8*)&PMh[off];
                al[s] = *(const short8*)&PMl[off];
            }
            f32x4v acc[4];
            #pragma unroll
            for (int cb = 0; cb < 4; ++cb) acc[cb] = (f32x4v){0.f,0.f,0.f,0.f};
            #pragma unroll
            for (int s = 0; s < 2; ++s)
                #pragma unroll
                for (int cb = 0; cb < 4; ++cb) {
                    const int off = (cb * 16 + l15) * LDB + 8 * lg + 32 * s;
                    const short8 bh = *(const short8*)&Wh[off];
                    const short8 bl = *(const short8*)&Wl[off];
                    acc[cb] = mfma16(ah[s], bh, acc[cb]);
                    acc[cb] = mfma16(al[s], bh, acc[cb]);
                    acc[cb] = mfma16(ah[s], bl, acc[cb]);
                }
            #pragma unroll
            for (int cb = 0; cb < 4; ++cb)
                #pragma unroll
                for (int reg = 0; reg < 4; ++reg) {
                    const int row = 16 * w + lg * 4 + reg;
                    const int col = cb * 16 + l15;
                    const float c = acc[cb][reg];
                    const unsigned short h = bf16rn(c);
                    PMh[row * LDB + col] = h;
                    PMl[row * LDB + col] = bf16rn(c - frombf(h));
                }
        }
        __syncthreads();

        if (t < 4) {   // phase2: M <- T*W (rows 64-127, in place)
            const int rb = 4 + (w >> 1);
            const int cb0 = (w & 1) << 1;
            short8 ah[2], al[2];
            #pragma unroll
            for (int s = 0; s < 2; ++s) {
                const int off = (rb * 16 + l15) * LDB + 8 * lg + 32 * s;
                ah[s] = *(const short8*)&PMh[off];
                al[s] = *(const short8*)&PMl[off];
            }
            __syncthreads();            // all T reads done before overwrite
            f32x4v acc[2];
            #pragma unroll
            for (int c2 = 0; c2 < 2; ++c2) acc[c2] = (f32x4v){0.f,0.f,0.f,0.f};
            #pragma unroll
            for (int s = 0; s < 2; ++s)
                #pragma unroll
                for (int c2 = 0; c2 < 2; ++c2) {
                    const int off = ((cb0 + c2) * 16 + l15) * LDB + 8 * lg + 32 * s;
                    const short8 bh = *(const short8*)&Wh[off];
                    const short8 bl = *(const short8*)&Wl[off];
                    acc[c2] = mfma16(ah[s], bh, acc[c2]);
                    acc[c2] = mfma16(al[s], bh, acc[c2]);
                    acc[c2] = mfma16(ah[s], bl, acc[c2]);
                }
            #pragma unroll
            for (int c2 = 0; c2 < 2; ++c2)
                #pragma unroll
                for (int reg = 0; reg < 4; ++reg) {
                    const int row = rb * 16 + lg * 4 + reg;
                    const int col = (cb0 + c2) * 16 + l15;
                    const float c = acc[c2][reg];
                    const unsigned short h = bf16rn(c);
                    PMh[row * LDB + col] = h;
                    PMl[row * LDB + col] = bf16rn(c - frombf(h));
                }
            __syncthreads();
        }
    }

    const float srtr = sqrtf(rtr);
    const float wr = weight[g * 64 + r];
    float* Wp = ws + WS_WM + g * 4096;
    float part = 0.0f;
    #pragma unroll
    for (int j = 0; j < 8; ++j) {
        const int c = ch + j;
        const float p = frombf(PMh[r * LDB + c]) + frombf(PMl[r * LDB + c]);
        const float wm = p * srtr;
        Wp[r * 64 + c] = wm * wr;
        part += wm * mean_s[c];
    }
    part += __shfl_down(part, 1, 8);
    part += __shfl_down(part, 2, 8);
    part += __shfl_down(part, 4, 8);
    if ((tid & 7) == 0)
        ws[WS_BETA + g * 64 + r] = bias[g * 64 + r] - wr * part;
}

// ---------------------------------------------------------------------------
// Kernel 3: apply. grid (196,4) x 256. NT f32x2 stores.
// ---------------------------------------------------------------------------
extern "C" __global__ __launch_bounds__(256, 4)
void k_apply(const float* __restrict__ X, const float* __restrict__ ws,
             float* __restrict__ out) {
    __shared__ __align__(16) unsigned short tx[2][2][64 * LDB];
    __shared__ __align__(16) float beta_sh[64];

    const int g = blockIdx.y, bx = blockIdx.x, tid = threadIdx.x;
    const int lane = tid & 63, w = tid >> 6;
    const int l15 = lane & 15, lg = lane >> 4;
    const float* Xg = X + (size_t)g * 64 * HWc;

    {   // stage wm fp32 -> bf16 into tx[0][0] (reused as x-tile later)
        unsigned short* wm_s = &tx[0][0][0];
        const float* Wp = ws + WS_WM + g * 4096;
        const int r = tid >> 2, chh = (tid & 3) << 4;
        const float* p = Wp + r * 64 + chh;
        const f32x4v v0 = *(const f32x4v*)(p);      const f32x4v v1 = *(const f32x4v*)(p + 4);
        const f32x4v v2 = *(const f32x4v*)(p + 8);  const f32x4v v3 = *(const f32x4v*)(p + 12);
        unsigned short* dst = &wm_s[r * LDB + chh];
        *(u32x4*)(dst)     = (u32x4){cvtpk(v0.x,v0.y), cvtpk(v0.z,v0.w),
                                     cvtpk(v1.x,v1.y), cvtpk(v1.z,v1.w)};
        *(u32x4*)(dst + 8) = (u32x4){cvtpk(v2.x,v2.y), cvtpk(v2.z,v2.w),
                                     cvtpk(v3.x,v3.y), cvtpk(v3.z,v3.w)};
        if (tid < 64) beta_sh[tid] = ws[WS_BETA + g * 64 + tid];
    }
    __syncthreads();

    const int CB0 = (w >> 1) << 1, MB0 = (w & 1) << 1;
    short8 afrag[2][2];
    {
        const unsigned short* wm_s = &tx[0][0][0];
        #pragma unroll
        for (int ci = 0; ci < 2; ++ci)
            #pragma unroll
            for (int s = 0; s < 2; ++s)
                afrag[ci][s] = *(const short8*)&wm_s[((CB0 + ci) * 16 + l15) * LDB + 8 * lg + 32 * s];
    }

    float betav[2][4]; int crow[2][4];
    #pragma unroll
    for (int ci = 0; ci < 2; ++ci)
        #pragma unroll
        for (int reg = 0; reg < 4; ++reg) {
            const int cl = (CB0 + ci) * 16 + lg * 4 + reg;
            betav[ci][reg] = beta_sh[cl];
            crow[ci][reg]  = (g * 64 + cl) * HWc;
        }
    __syncthreads();   // frag/beta reads done before tx[0][0] is overwritten

    const int qq = lane >> 4, ss = lane & 15;
    const int ecol = 16 * w + 4 * qq;
    int eoff[4], woff[4];
    #pragma unroll
    for (int jj = 0; jj < 4; ++jj) eoff[jj] = (ecol + jj) * HWc + 4 * ss;
    #pragma unroll
    for (int i = 0; i < 4; ++i) {
        const int m = 4 * ss + i;
        const int rT = 32 * (m >> 5) + 16 * (m & 1) + ((m & 31) >> 1);
        woff[i] = rT * LDB + ecol;
    }
    const int mcb = 32 * (w & 1) + 2 * l15;            // store col base

    f32x4v curA[4], curB[4];
    auto loadt = [&](int t, f32x4v* cur) {
        const int b = t / 49, hw0 = (t - b * 49) << 6;
        const float* p = Xg + (size_t)b * CHW + hw0;
        #pragma unroll
        for (int jj = 0; jj < 4; ++jj)
            cur[jj] = *(const f32x4v*)(p + eoff[jj]);
    };
    auto packt = [&](const f32x4v* cur, unsigned short* dstbuf) {
        #pragma unroll
        for (int i = 0; i < 4; ++i) {
            const u32x2 d = {cvtpk(cur[0][i], cur[1][i]),
                             cvtpk(cur[2][i], cur[3][i])};
            *(u32x2*)&dstbuf[woff[i]] = d;
        }
    };
    auto compst = [&](const unsigned short* T, int t) {
        f32x4v acc[2][2];
        #pragma unroll
        for (int i = 0; i < 2; ++i)
            #pragma unroll
            for (int j = 0; j < 2; ++j) acc[i][j] = (f32x4v){0.f,0.f,0.f,0.f};
        #pragma unroll
        for (int s = 0; s < 2; ++s) {
            const int ko = 8 * lg + 32 * s;
            const short8 b0 = *(const short8*)&T[(MB0 * 16     + l15) * LDB + ko];
            const short8 b1 = *(const short8*)&T[((MB0+1) * 16 + l15) * LDB + ko];
            acc[0][0] = mfma16(afrag[0][s], b0, acc[0][0]);
            acc[0][1] = mfma16(afrag[0][s], b1, acc[0][1]);
            acc[1][0] = mfma16(afrag[1][s], b0, acc[1][0]);
            acc[1][1] = mfma16(afrag[1][s], b1, acc[1][1]);
        }
        const int b = t / 49, hw0 = (t - b * 49) << 6;
        float* ob = out + (size_t)b * CHW + hw0 + mcb;
        #pragma unroll
        for (int ci = 0; ci < 2; ++ci)
            #pragma unroll
            for (int reg = 0; reg < 4; ++reg) {
                const float bt = betav[ci][reg];
                const f32x2v v = {acc[ci][0][reg] + bt, acc[ci][1][reg] + bt};
                __builtin_nontemporal_store(v, (f32x2v*)(ob + crow[ci][reg]));
            }
    };

    loadt(bx, curA);
    loadt(bx + GX, curB);

    int buf = 0;
    for (int kk = 0; kk < 8; ++kk) {
        packt(curA, tx[buf][0]);
        packt(curB, tx[buf][1]);
        __syncthreads();
        if (kk < 7) {
            loadt(bx + GX * (2*kk + 2), curA);
            loadt(bx + GX * (2*kk + 3), curB);
        }
        compst(tx[buf][0], bx + GX * (2*kk));
        compst(tx[buf][1], bx + GX * (2*kk + 1));
        buf ^= 1;
    }
}

// ---------------------------------------------------------------------------
extern "C" void kernel_launch(void* const* d_in, const int* in_sizes, int n_in,
                              void* d_out, int out_size, void* d_ws, size_t ws_size,
                              hipStream_t stream) {
    const float* X      = (const float*)d_in[0];
    const float* weight = (const float*)d_in[1];
    const float* bias   = (const float*)d_in[2];
    float* out = (float*)d_out;
    float* ws  = (float*)d_ws;

    hipLaunchKernelGGL(k_gram,   dim3(GX, 4), dim3(256), 0, stream, X, ws);
    hipLaunchKernelGGL(k_reduce, dim3(64, 4), dim3(256), 0, stream, ws);
    hipLaunchKernelGGL(k_solve,  dim3(4),     dim3(512), 0, stream, weight, bias, ws);
    hipLaunchKernelGGL(k_apply,  dim3(GX, 4), dim3(256), 0, stream, X, ws, out);
    // PROBE: duplicate launch (idempotent). dur_us delta vs R10 == k_apply cost.
    hipLaunchKernelGGL(k_apply,  dim3(GX, 4), dim3(256), 0, stream, X, ws, out);
}

// Round 12
// 132.096 us; speedup vs baseline: 1.5494x; 1.5494x over previous
//
#include <hip/hip_runtime.h>
#include <hip/hip_bf16.h>
#include <math.h>

// ---------------------------------------------------------------------------
// IterNorm (64,256,56,56) fp32, g=4 groups of 64 channels.
//  k_gram  : partial Gram + channel sums -> slabs [measured: 34.6us, at floor]
//  k_reduce: sum 196 slabs/group -> G, SUM
//  k_solve : Newton-Schulz, W folded away: N=-0.5M; per iter (3 barriers):
//            phase1 (no entry barrier): [P_new;T] = 1.5[P;N] + [P;N]*N
//            phase2: N_new = 1.5T + T*N. hi/lo bf16 split, fp32 accum.
//  k_apply : [measured: 70.4us] 1c x 4m wave layout; TX row=(m&3)*16+(m>>2)
//            so D cols transpose into f32x4 NT stores (16B/lane).
// MFMA 16x16x32_bf16 layouts (HW-verified): A/B-frag lane l: row l&15,
// k=(l>>4)*8+j ; C/D: col=l&15, row=(l>>4)*4+reg.
// ---------------------------------------------------------------------------

#define EPS_F 1e-5f

using f32x4v = __attribute__((ext_vector_type(4))) float;
using f32x2v = __attribute__((ext_vector_type(2))) float;
using short8 = __attribute__((ext_vector_type(8))) short;
using u32x4  = __attribute__((ext_vector_type(4))) unsigned int;
using u32x2  = __attribute__((ext_vector_type(2))) unsigned int;

constexpr int Cc  = 256;
constexpr int HWc = 3136;                 // 56*56
constexpr int CHW = Cc * HWc;             // 802816
constexpr float Mf = 200704.0f;           // 64*3136
constexpr int GX  = 196;                  // 3136 tiles / 196 = 16 tiles/block
constexpr int LDB = 72;                   // bf16 LDS row stride (144 B)

// workspace layout (float offsets)
constexpr int WS_SUM  = 0;                       // 256
constexpr int WS_G    = 256;                     // 4*4096
constexpr int WS_WM   = WS_G + 16384;            // 4*4096
constexpr int WS_BETA = WS_WM + 16384;           // 256
constexpr int WS_SLAB = WS_BETA + 256;           // 784 * 4096 partial Grams
constexpr int WS_SSUM = WS_SLAB + 784 * 4096;    // 784 * 64 partial channel sums

__device__ __forceinline__ unsigned cvtpk(float lo, float hi) {
    __hip_bfloat162 h = __float22bfloat162_rn(float2{lo, hi});
    unsigned u;
    __builtin_memcpy(&u, &h, 4);
    return u;
}

__device__ __forceinline__ unsigned short bf16rn(float v) {
    unsigned u = __builtin_bit_cast(unsigned, v);
    u += 0x7FFFu + ((u >> 16) & 1u);
    return (unsigned short)(u >> 16);
}
__device__ __forceinline__ float frombf(unsigned short h) {
    unsigned u = (unsigned)h << 16;
    return __builtin_bit_cast(float, u);
}

__device__ __forceinline__ f32x4v mfma16(short8 a, short8 b, f32x4v c) {
    return __builtin_amdgcn_mfma_f32_16x16x32_bf16(a, b, c, 0, 0, 0);
}

// ---------------------------------------------------------------------------
// Kernel 1: partial Gram. grid (196,4) x 256 (4 waves). [at HBM floor]
// ---------------------------------------------------------------------------
extern "C" __global__ __launch_bounds__(256, 4)
void k_gram(const float* __restrict__ X, float* __restrict__ ws) {
    __shared__ __align__(16) unsigned short tg[2][2][64 * LDB];
    const int g = blockIdx.y, bx = blockIdx.x, tid = threadIdx.x;
    const int lane = tid & 63, w = tid >> 6;
    const int row = tid >> 2, mo = (tid & 3) << 4;     // load mapping
    const int l15 = lane & 15, lg = lane >> 4;
    const int CBi0 = (w >> 1) << 1, CBj0 = (w & 1) << 1;
    const float* Xg = X + (size_t)g * 64 * HWc;

    f32x4v acc[2][2];
    #pragma unroll
    for (int i = 0; i < 2; ++i)
        #pragma unroll
        for (int j = 0; j < 2; ++j) acc[i][j] = (f32x4v){0.f, 0.f, 0.f, 0.f};
    float csum = 0.0f;

    f32x4v curA[4], curB[4];
    auto loadt = [&](int t, f32x4v* cur) {
        const int b = t / 49, hw0 = (t - b * 49) << 6;
        const float* p = Xg + (size_t)b * CHW + (size_t)row * HWc + hw0 + mo;
        cur[0] = *(const f32x4v*)(p);      cur[1] = *(const f32x4v*)(p + 4);
        cur[2] = *(const f32x4v*)(p + 8);  cur[3] = *(const f32x4v*)(p + 12);
    };
    auto packt = [&](const f32x4v* cur, unsigned short* dstbuf) {
        unsigned pk[8];
        #pragma unroll
        for (int i = 0; i < 4; ++i) {
            csum += (cur[i].x + cur[i].y) + (cur[i].z + cur[i].w);
            pk[2*i]   = cvtpk(cur[i].x, cur[i].y);
            pk[2*i+1] = cvtpk(cur[i].z, cur[i].w);
        }
        unsigned short* dst = dstbuf + row * LDB + mo;
        *(u32x4*)(dst)     = (u32x4){pk[0], pk[1], pk[2], pk[3]};
        *(u32x4*)(dst + 8) = (u32x4){pk[4], pk[5], pk[6], pk[7]};
    };
    auto comp = [&](const unsigned short* T) {
        #pragma unroll
        for (int s = 0; s < 2; ++s) {
            const int ko = 8 * lg + 32 * s;
            const short8 a0 = *(const short8*)&T[(CBi0 * 16      + l15) * LDB + ko];
            const short8 a1 = *(const short8*)&T[((CBi0+1) * 16  + l15) * LDB + ko];
            const short8 b0 = *(const short8*)&T[(CBj0 * 16      + l15) * LDB + ko];
            const short8 b1 = *(const short8*)&T[((CBj0+1) * 16  + l15) * LDB + ko];
            acc[0][0] = mfma16(a0, b0, acc[0][0]);
            acc[0][1] = mfma16(a0, b1, acc[0][1]);
            acc[1][0] = mfma16(a1, b0, acc[1][0]);
            acc[1][1] = mfma16(a1, b1, acc[1][1]);
        }
    };

    loadt(bx, curA);
    loadt(bx + GX, curB);

    int buf = 0;
    for (int kk = 0; kk < 8; ++kk) {
        packt(curA, tg[buf][0]);
        packt(curB, tg[buf][1]);
        __syncthreads();
        if (kk < 7) {
            loadt(bx + GX * (2*kk + 2), curA);
            loadt(bx + GX * (2*kk + 3), curB);
        }
        comp(tg[buf][0]);
        comp(tg[buf][1]);
        buf ^= 1;
    }

    csum += __shfl_down(csum, 1, 4);
    csum += __shfl_down(csum, 2, 4);
    if ((tid & 3) == 0)
        ws[WS_SSUM + (g * GX + bx) * 64 + row] = csum;

    float* Gp = ws + WS_SLAB + (size_t)(g * GX + bx) * 4096;
    #pragma unroll
    for (int ci = 0; ci < 2; ++ci)
        #pragma unroll
        for (int cj = 0; cj < 2; ++cj)
            #pragma unroll
            for (int reg = 0; reg < 4; ++reg) {
                const int r = (CBi0 + ci) * 16 + lg * 4 + reg;
                const int c = (CBj0 + cj) * 16 + l15;
                Gp[r * 64 + c] = acc[ci][cj][reg];
            }
}

// ---------------------------------------------------------------------------
// Kernel 1b: reduce slabs. grid (64,4) x 256.
// ---------------------------------------------------------------------------
extern "C" __global__ __launch_bounds__(256)
void k_reduce(float* __restrict__ ws) {
    __shared__ float part[4][64];
    const int g = blockIdx.y, chunk = blockIdx.x, tid = threadIdx.x;
    const int c63 = tid & 63, q = tid >> 6;
    const float* p = ws + WS_SLAB + (size_t)g * GX * 4096
                   + (size_t)(q * 49) * 4096 + chunk * 64 + c63;
    float s = 0.f;
    #pragma unroll 7
    for (int i = 0; i < 49; ++i) { s += *p; p += 4096; }
    part[q][c63] = s;
    __syncthreads();
    if (tid < 64)
        ws[WS_G + g * 4096 + chunk * 64 + tid] =
            (part[0][tid] + part[1][tid]) + (part[2][tid] + part[3][tid]);

    if (chunk == 0 && tid < 64) {
        const float* qq = ws + WS_SSUM + (size_t)g * GX * 64 + tid;
        float a0 = 0.f, a1 = 0.f, a2 = 0.f, a3 = 0.f;
        #pragma unroll 7
        for (int s4 = 0; s4 < 49; ++s4) {
            a0 += qq[0];
            a1 += qq[64];
            a2 += qq[128];
            a3 += qq[192];
            qq += 256;
        }
        ws[WS_SUM + g * 64 + tid] = (a0 + a1) + (a2 + a3);
    }
}

// ---------------------------------------------------------------------------
// Kernel 2: Newton-Schulz, W folded. 4 blocks x 512 (8 waves).
// PN rows 0-63 = P, rows 64-127 = N (= -0.5*Sigma_N at t=0).
// phase1: wave w: own 16-row stacked block: X_own <- 1.5*X_own + X_own*N
//         (waves 0-3 write P in place; waves 4-7 write T buffer; B=N untouched
//          -> NO entry barrier). barrier.
// phase2 (t<4): N <- 1.5*T + T*N; preload A/B/C frags, barrier, MFMA, write,
//         barrier.
// ---------------------------------------------------------------------------
extern "C" __global__ __launch_bounds__(512)
void k_solve(const float* __restrict__ weight, const float* __restrict__ bias,
             float* __restrict__ ws) {
    __shared__ __align__(16) unsigned short PNh[128 * LDB], PNl[128 * LDB];
    __shared__ __align__(16) unsigned short Th[64 * LDB], Tl[64 * LDB];
    __shared__ float mean_s[64], diag_s[64];
    __shared__ float red;

    const int g = blockIdx.x, tid = threadIdx.x;
    const int lane = tid & 63, w = tid >> 6;
    const int l15 = lane & 15, lg = lane >> 4;
    const int r = tid >> 3, ch8 = (tid & 7) << 3;   // elementwise: row r, 8 cols

    if (tid < 64) mean_s[tid] = ws[WS_SUM + g * 64 + tid] * (1.0f / Mf);
    __syncthreads();

    const float* Gp = ws + WS_G + g * 4096;
    const float mr = mean_s[r];
    float sv[8];
    #pragma unroll
    for (int j = 0; j < 8; ++j) {
        const int c = ch8 + j;
        float v = Gp[r * 64 + c] * (1.0f / Mf) - mr * mean_s[c];
        if (c == r) { v += EPS_F; diag_s[r] = v; }
        sv[j] = v;
    }
    __syncthreads();
    if (tid == 0) {
        float tr = 0.f;
        #pragma unroll
        for (int i = 0; i < 64; ++i) tr += diag_s[i];
        red = 1.0f / tr;
    }
    __syncthreads();
    const float rtr = red;

    // P = I (rows 0-63); N = -0.5*Sigma*rtr (rows 64-127), hi/lo
    #pragma unroll
    for (int j = 0; j < 8; ++j) {
        const int c = ch8 + j;
        PNh[r * LDB + c] = (c == r) ? (unsigned short)0x3F80 : (unsigned short)0;
        PNl[r * LDB + c] = 0;
        const float v = sv[j] * rtr * (-0.5f);
        const unsigned short h = bf16rn(v);
        PNh[(64 + r) * LDB + c] = h;
        PNl[(64 + r) * LDB + c] = bf16rn(v - frombf(h));
    }
    __syncthreads();

    for (int t = 0; t < 5; ++t) {
        {   // ---- phase1 (no entry barrier) ----
            short8 ah[2], al[2];
            #pragma unroll
            for (int s = 0; s < 2; ++s) {
                const int off = (16 * w + l15) * LDB + 8 * lg + 32 * s;
                ah[s] = *(const short8*)&PNh[off];
                al[s] = *(const short8*)&PNl[off];
            }
            f32x4v acc[4];
            #pragma unroll
            for (int cb = 0; cb < 4; ++cb)
                #pragma unroll
                for (int reg = 0; reg < 4; ++reg) {
                    const int row = 16 * w + 4 * lg + reg;
                    const int col = cb * 16 + l15;
                    acc[cb][reg] = 1.5f * (frombf(PNh[row * LDB + col])
                                         + frombf(PNl[row * LDB + col]));
                }
            #pragma unroll
            for (int s = 0; s < 2; ++s)
                #pragma unroll
                for (int cb = 0; cb < 4; ++cb) {
                    const int off = (64 + cb * 16 + l15) * LDB + 8 * lg + 32 * s;
                    const short8 bh = *(const short8*)&PNh[off];
                    const short8 bl = *(const short8*)&PNl[off];
                    acc[cb] = mfma16(ah[s], bh, acc[cb]);
                    acc[cb] = mfma16(al[s], bh, acc[cb]);
                    acc[cb] = mfma16(ah[s], bl, acc[cb]);
                }
            #pragma unroll
            for (int cb = 0; cb < 4; ++cb)
                #pragma unroll
                for (int reg = 0; reg < 4; ++reg) {
                    const int row = 16 * w + 4 * lg + reg;
                    const int col = cb * 16 + l15;
                    const float c = acc[cb][reg];
                    const unsigned short h = bf16rn(c);
                    if (w < 4) {                   // P_new in place
                        PNh[row * LDB + col] = h;
                        PNl[row * LDB + col] = bf16rn(c - frombf(h));
                    } else {                       // T buffer
                        Th[(row - 64) * LDB + col] = h;
                        Tl[(row - 64) * LDB + col] = bf16rn(c - frombf(h));
                    }
                }
        }
        __syncthreads();                           // B1

        if (t < 4) {   // ---- phase2: N <- 1.5T + T*N ----
            const int rb = w >> 1;
            const int cb0 = (w & 1) << 1;
            short8 tah[2], tal[2];
            #pragma unroll
            for (int s = 0; s < 2; ++s) {
                const int off = (rb * 16 + l15) * LDB + 8 * lg + 32 * s;
                tah[s] = *(const short8*)&Th[off];
                tal[s] = *(const short8*)&Tl[off];
            }
            short8 bh[2][2], bl[2][2];
            #pragma unroll
            for (int c2 = 0; c2 < 2; ++c2)
                #pragma unroll
                for (int s = 0; s < 2; ++s) {
                    const int off = (64 + (cb0 + c2) * 16 + l15) * LDB + 8 * lg + 32 * s;
                    bh[c2][s] = *(const short8*)&PNh[off];
                    bl[c2][s] = *(const short8*)&PNl[off];
                }
            f32x4v acc[2];
            #pragma unroll
            for (int c2 = 0; c2 < 2; ++c2)
                #pragma unroll
                for (int reg = 0; reg < 4; ++reg) {
                    const int row = rb * 16 + 4 * lg + reg;
                    const int col = (cb0 + c2) * 16 + l15;
                    acc[c2][reg] = 1.5f * (frombf(Th[row * LDB + col])
                                         + frombf(Tl[row * LDB + col]));
                }
            __syncthreads();                       // B2: N reads done
            #pragma unroll
            for (int s = 0; s < 2; ++s)
                #pragma unroll
                for (int c2 = 0; c2 < 2; ++c2) {
                    acc[c2] = mfma16(tah[s], bh[c2][s], acc[c2]);
                    acc[c2] = mfma16(tal[s], bh[c2][s], acc[c2]);
                    acc[c2] = mfma16(tah[s], bl[c2][s], acc[c2]);
                }
            #pragma unroll
            for (int c2 = 0; c2 < 2; ++c2)
                #pragma unroll
                for (int reg = 0; reg < 4; ++reg) {
                    const int row = 64 + rb * 16 + 4 * lg + reg;
                    const int col = (cb0 + c2) * 16 + l15;
                    const float c = acc[c2][reg];
                    const unsigned short h = bf16rn(c);
                    PNh[row * LDB + col] = h;
                    PNl[row * LDB + col] = bf16rn(c - frombf(h));
                }
            __syncthreads();                       // B3
        }
    }

    // fold weight/bias/mean (P = rows 0-63)
    const float srtr = sqrtf(rtr);
    const float wr = weight[g * 64 + r];
    float* Wp = ws + WS_WM + g * 4096;
    float part = 0.0f;
    #pragma unroll
    for (int j = 0; j < 8; ++j) {
        const int c = ch8 + j;
        const float p = frombf(PNh[r * LDB + c]) + frombf(PNl[r * LDB + c]);
        const float wm = p * srtr;
        Wp[r * 64 + c] = wm * wr;
        part += wm * mean_s[c];
    }
    part += __shfl_down(part, 1, 8);
    part += __shfl_down(part, 2, 8);
    part += __shfl_down(part, 4, 8);
    if ((tid & 7) == 0)
        ws[WS_BETA + g * 64 + r] = bias[g * 64 + r] - wr * part;
}

// ---------------------------------------------------------------------------
// Kernel 3: apply. grid (196,4) x 256. Wave w = c-block w x 4 m-blocks.
// TX row (m&3)*16 + (m>>2): tile-col c of m-block mb holds m=4c+mb, so the
// 4 accs per reg form one f32x4 NT store at 4*l15 (16B/lane, coalesced).
// ---------------------------------------------------------------------------
extern "C" __global__ __launch_bounds__(256, 4)
void k_apply(const float* __restrict__ X, const float* __restrict__ ws,
             float* __restrict__ out) {
    __shared__ __align__(16) unsigned short tx[2][2][64 * LDB];
    __shared__ __align__(16) float beta_sh[64];

    const int g = blockIdx.y, bx = blockIdx.x, tid = threadIdx.x;
    const int lane = tid & 63, w = tid >> 6;
    const int l15 = lane & 15, lg = lane >> 4;
    const float* Xg = X + (size_t)g * 64 * HWc;

    {   // stage wm fp32 -> bf16 into tx[0][0] (reused as x-tile later)
        unsigned short* wm_s = &tx[0][0][0];
        const float* Wp = ws + WS_WM + g * 4096;
        const int r = tid >> 2, chh = (tid & 3) << 4;
        const float* p = Wp + r * 64 + chh;
        const f32x4v v0 = *(const f32x4v*)(p);      const f32x4v v1 = *(const f32x4v*)(p + 4);
        const f32x4v v2 = *(const f32x4v*)(p + 8);  const f32x4v v3 = *(const f32x4v*)(p + 12);
        unsigned short* dst = &wm_s[r * LDB + chh];
        *(u32x4*)(dst)     = (u32x4){cvtpk(v0.x,v0.y), cvtpk(v0.z,v0.w),
                                     cvtpk(v1.x,v1.y), cvtpk(v1.z,v1.w)};
        *(u32x4*)(dst + 8) = (u32x4){cvtpk(v2.x,v2.y), cvtpk(v2.z,v2.w),
                                     cvtpk(v3.x,v3.y), cvtpk(v3.z,v3.w)};
        if (tid < 64) beta_sh[tid] = ws[WS_BETA + g * 64 + tid];
    }
    __syncthreads();

    short8 afrag[2];
    {
        const unsigned short* wm_s = &tx[0][0][0];
        #pragma unroll
        for (int s = 0; s < 2; ++s)
            afrag[s] = *(const short8*)&wm_s[(16 * w + l15) * LDB + 8 * lg + 32 * s];
    }
    float betav[4]; int crow[4];
    #pragma unroll
    for (int reg = 0; reg < 4; ++reg) {
        const int cl = 16 * w + lg * 4 + reg;
        betav[reg] = beta_sh[cl];
        crow[reg]  = (g * 64 + cl) * HWc;
    }
    __syncthreads();   // frag/beta reads done before tx[0][0] is overwritten

    // staging: lane (qq,ss) loads e-rows ecol..ecol+3, m = 4ss..4ss+3;
    // m -> TX row (m&3)*16 + (m>>2)
    const int qq = lane >> 4, ss = lane & 15;
    const int ecol = 16 * w + 4 * qq;
    int eoff[4], woff[4];
    #pragma unroll
    for (int jj = 0; jj < 4; ++jj) eoff[jj] = (ecol + jj) * HWc + 4 * ss;
    #pragma unroll
    for (int i = 0; i < 4; ++i) woff[i] = (i * 16 + ss) * LDB + ecol;

    f32x4v curA[4], curB[4];
    auto loadt = [&](int t, f32x4v* cur) {
        const int b = t / 49, hw0 = (t - b * 49) << 6;
        const float* p = Xg + (size_t)b * CHW + hw0;
        #pragma unroll
        for (int jj = 0; jj < 4; ++jj)
            cur[jj] = *(const f32x4v*)(p + eoff[jj]);
    };
    auto packt = [&](const f32x4v* cur, unsigned short* dstbuf) {
        #pragma unroll
        for (int i = 0; i < 4; ++i) {
            const u32x2 d = {cvtpk(cur[0][i], cur[1][i]),
                             cvtpk(cur[2][i], cur[3][i])};
            *(u32x2*)&dstbuf[woff[i]] = d;
        }
    };
    auto compst = [&](const unsigned short* T, int t) {
        f32x4v acc[4];
        #pragma unroll
        for (int mb = 0; mb < 4; ++mb) acc[mb] = (f32x4v){0.f,0.f,0.f,0.f};
        #pragma unroll
        for (int s = 0; s < 2; ++s) {
            const int ko = 8 * lg + 32 * s;
            #pragma unroll
            for (int mb = 0; mb < 4; ++mb) {
                const short8 b = *(const short8*)&T[(mb * 16 + l15) * LDB + ko];
                acc[mb] = mfma16(afrag[s], b, acc[mb]);
            }
        }
        const int b = t / 49, hw0 = (t - b * 49) << 6;
        float* ob = out + (size_t)b * CHW + hw0 + 4 * l15;
        #pragma unroll
        for (int reg = 0; reg < 4; ++reg) {
            const float bt = betav[reg];
            const f32x4v v = {acc[0][reg] + bt, acc[1][reg] + bt,
                              acc[2][reg] + bt, acc[3][reg] + bt};
            __builtin_nontemporal_store(v, (f32x4v*)(ob + crow[reg]));
        }
    };

    loadt(bx, curA);
    loadt(bx + GX, curB);

    int buf = 0;
    for (int kk = 0; kk < 8; ++kk) {
        packt(curA, tx[buf][0]);
        packt(curB, tx[buf][1]);
        __syncthreads();
        if (kk < 7) {
            loadt(bx + GX * (2*kk + 2), curA);
            loadt(bx + GX * (2*kk + 3), curB);
        }
        compst(tx[buf][0], bx + GX * (2*kk));
        compst(tx[buf][1], bx + GX * (2*kk + 1));
        buf ^= 1;
    }
}

// ---------------------------------------------------------------------------
extern "C" void kernel_launch(void* const* d_in, const int* in_sizes, int n_in,
                              void* d_out, int out_size, void* d_ws, size_t ws_size,
                              hipStream_t stream) {
    const float* X      = (const float*)d_in[0];
    const float* weight = (const float*)d_in[1];
    const float* bias   = (const float*)d_in[2];
    float* out = (float*)d_out;
    float* ws  = (float*)d_ws;

    hipLaunchKernelGGL(k_gram,   dim3(GX, 4), dim3(256), 0, stream, X, ws);
    hipLaunchKernelGGL(k_reduce, dim3(64, 4), dim3(256), 0, stream, ws);
    hipLaunchKernelGGL(k_solve,  dim3(4),     dim3(512), 0, stream, weight, bias, ws);
    hipLaunchKernelGGL(k_apply,  dim3(GX, 4), dim3(256), 0, stream, X, ws, out);
}